// Round 5
// baseline (1362.805 us; speedup 1.0000x reference)
//
#include <hip/hip_runtime.h>

#define HID   128
#define SEQL  512
#define MT    16
#define TPB   512
#define BATCH 1024

typedef __attribute__((ext_vector_type(4))) float    f32x4;
typedef __attribute__((ext_vector_type(8))) _Float16 f16x8;

union Pack8 { int2 p2[2]; int4 p4; f16x8 h; _Float16 hf[8]; short s[8]; };

__device__ __forceinline__ short f2hs(float f) {
    _Float16 v = (_Float16)f;
    return __builtin_bit_cast(short, v);
}
// R3-proven activations (inf-safe; compiler-generated TRANS ops only)
__device__ __forceinline__ float fsig(float x) {
    return __builtin_amdgcn_rcpf(1.f + __expf(-x));
}
__device__ __forceinline__ float ftanh(float x) {
    return 1.f - 2.f * __builtin_amdgcn_rcpf(1.f + __expf(2.f * x));
}

// Repack weights into per-lane MFMA B-frag layout (fp16, UNSCALED — R3 datapath),
// sum biases, pre-pack x into fp16 A-frags (same RTN rounding as in-kernel cast).
// 16x16x32 operand layout: lane l holds col=l&15, elem i -> k = kk*32 + 8*(l>>4) + i.
__global__ void prep_kernel(const float* __restrict__ x,
                            const float* __restrict__ w_ih0, const float* __restrict__ w_hh0,
                            const float* __restrict__ b_ih0, const float* __restrict__ b_hh0,
                            const float* __restrict__ w_ih1, const float* __restrict__ w_hh1,
                            const float* __restrict__ b_ih1, const float* __restrict__ b_hh1,
                            short* __restrict__ recW0, short* __restrict__ recW1,
                            short* __restrict__ inW1, short* __restrict__ xW0,
                            float* __restrict__ bias0, float* __restrict__ bias1,
                            short* __restrict__ xf) {
    int tid = blockIdx.x * 256 + threadIdx.x;
    if (tid < 2097152) {                    // x -> f16 frags [grp][t][c][g4][8]
        int g4 = tid & 3, c = (tid >> 2) & 15, t = (tid >> 6) & 511, grp = tid >> 15;
        const float* src = x + ((size_t)(grp * 16 + c) * 512 + t) * 32 + g4 * 8;
        Pack8 p;
        #pragma unroll
        for (int i = 0; i < 8; ++i) p.hf[i] = (_Float16)src[i];
        *(int4*)(xf + (size_t)tid * 8) = p.p4;
    } else if (tid < 2121728) {             // 3 matrices of [8w][4g][4kk][64lane][8]
        int q = tid - 2097152;
        int m = q >> 13;
        int r = q & 8191;
        int lane = r & 63, kk = (r >> 6) & 3, g = (r >> 8) & 3, w = r >> 10;
        int c = lane & 15, g4 = lane >> 4;
        int col = g * 128 + w * 16 + c;
        const float* src = (m == 0) ? w_hh0 : (m == 1) ? w_hh1 : w_ih1;
        short* dst = ((m == 0) ? recW0 : (m == 1) ? recW1 : inW1) + (size_t)r * 8;
        #pragma unroll
        for (int i = 0; i < 8; ++i)
            dst[i] = f2hs(src[col * 128 + kk * 32 + 8 * g4 + i]);
    } else if (tid < 2123776) {             // xW0: [8w][4g][64lane][8], K=32
        int r = tid - 2121728;
        int lane = r & 63, g = (r >> 6) & 3, w = r >> 8;
        int c = lane & 15, g4 = lane >> 4;
        int col = g * 128 + w * 16 + c;
        short* dst = xW0 + (size_t)r * 8;
        #pragma unroll
        for (int i = 0; i < 8; ++i)
            dst[i] = f2hs(w_ih0[col * 32 + 8 * g4 + i]);
    } else if (tid < 2124288) {
        int j = tid - 2123776;
        bias0[j] = b_ih0[j] + b_hh0[j];
    } else if (tid < 2124800) {
        int j = tid - 2124288;
        bias1[j] = b_ih1[j] + b_hh1[j];
    }
}

// Fused 2-layer LSTM, one block = 16 batch rows. Iter t: L0 step t, L1 step
// t-1 (shares the ah0 A-frags). Wave w owns units [16w,16w+16) in all 4 gate
// regions of both layers -> lane-local c/h update. Per-iter program order
// interleaves L0's activation VALU into L1's MFMA stream so the 2 waves/SIMD
// can co-issue on separate pipes. One barrier per iter.
__global__ __launch_bounds__(TPB, 2) void fused_lstm_kernel(
    const short* __restrict__ xf,
    const short* __restrict__ recW0g, const short* __restrict__ recW1g,
    const short* __restrict__ inW1g,  const short* __restrict__ xW0g,
    const float* __restrict__ bias0,  const float* __restrict__ bias1,
    const float* __restrict__ fc1_w, const float* __restrict__ fc1_b,
    const float* __restrict__ fc2_w, const float* __restrict__ fc2_b,
    float* __restrict__ out)
{
    extern __shared__ char smem[];
    short* inL = (short*)smem;                   // 128 KB: inW1 B-frags
    char*  hS0 = smem + 131072;                  // 2 x 4 KB fp16 h0 state
    char*  hS1 = smem + 139264;                  // 2 x 4 KB fp16 h1 state

    const int tid = threadIdx.x;
    const int w = tid >> 6, lane = tid & 63;
    const int c = lane & 15, g4 = lane >> 4;
    const int row0 = blockIdx.x * MT;

    // stage inW1 into LDS (16384 int4)
    #pragma unroll
    for (int i = 0; i < 32; ++i)
        ((int4*)inL)[i * TPB + tid] = ((const int4*)inW1g)[i * TPB + tid];
    // zero h0/h1 double buffers (16 KB)
    #pragma unroll
    for (int i = 0; i < 8; ++i)
        ((int*)hS0)[i * TPB + tid] = 0;

    // loop-invariant register weights
    Pack8 recW0f[4][4], recW1f[4][4], xWf[4];
    #pragma unroll
    for (int g = 0; g < 4; ++g)
        #pragma unroll
        for (int kk = 0; kk < 4; ++kk) {
            recW0f[g][kk].p4 = *(const int4*)(recW0g + (size_t)((((w*4+g)*4+kk)*64 + lane) * 8));
            recW1f[g][kk].p4 = *(const int4*)(recW1g + (size_t)((((w*4+g)*4+kk)*64 + lane) * 8));
        }
    #pragma unroll
    for (int g = 0; g < 4; ++g)
        xWf[g].p4 = *(const int4*)(xW0g + (size_t)(((w*4+g)*64 + lane) * 8));

    float biasr0[4], biasr1[4];
    #pragma unroll
    for (int g = 0; g < 4; ++g) {
        biasr0[g] = bias0[g*128 + w*16 + c];
        biasr1[g] = bias1[g*128 + w*16 + c];
    }

    __syncthreads();

    float cst0[4] = {0.f, 0.f, 0.f, 0.f};
    float cst1[4] = {0.f, 0.f, 0.f, 0.f};

    const short* xfp = xf + (size_t)blockIdx.x * 262144 + c * 32 + g4 * 8;

    const int swz   = (c & 14) << 3;
    const int rbase = c * 256;
    const int unit  = w * 16 + c;
    int woff[4];
    #pragma unroll
    for (int r = 0; r < 4; ++r) {
        int rrow = 4 * g4 + r;
        woff[r] = rrow * 256 + ((unit * 2) ^ ((rrow & 14) << 3));
    }
    const int inBbase = w * 16384;

    Pack8 xv, xn;
    xv.p4 = *(const int4*)(xfp);
    xn.p4 = *(const int4*)(xfp + 512);

    // ---- peel t=0: L0 only (h0(-1)=0 in zeroed buf0) ----
    {
        Pack8 ah0[4];
        #pragma unroll
        for (int kk = 0; kk < 4; ++kk)
            ah0[kk].p4 = *(const int4*)(hS0 + (rbase + ((kk*64 + 16*g4) ^ swz)));
        f32x4 acc0[4];
        #pragma unroll
        for (int g = 0; g < 4; ++g) { float b = biasr0[g]; acc0[g] = (f32x4){b,b,b,b}; }
        #pragma unroll
        for (int g = 0; g < 4; ++g)
            acc0[g] = __builtin_amdgcn_mfma_f32_16x16x32_f16(xv.h, xWf[g].h, acc0[g], 0, 0, 0);
        #pragma unroll
        for (int kk = 0; kk < 4; ++kk)
            #pragma unroll
            for (int g = 0; g < 4; ++g)
                acc0[g] = __builtin_amdgcn_mfma_f32_16x16x32_f16(ah0[kk].h, recW0f[g][kk].h, acc0[g], 0, 0, 0);
        char* h0w = hS0 + 4096;
        #pragma unroll
        for (int r = 0; r < 4; ++r) {
            float si = fsig(acc0[0][r]), sf = fsig(acc0[1][r]);
            float tg = ftanh(acc0[2][r]), so = fsig(acc0[3][r]);
            float cc = sf * cst0[r] + si * tg;
            cst0[r] = cc;
            float hh = so * ftanh(cc);
            *(_Float16*)(h0w + woff[r]) = (_Float16)hh;
        }
        __syncthreads();
    }

    // ---- steady iters t=1..511: L0 step t + L1 step t-1 ----
    for (int t = 1; t < SEQL; ++t) {
        const int rb = t & 1;
        const char* h0r = hS0 + rb * 4096;
        const char* h1r = hS1 + rb * 4096;
        char* h0w = hS0 + (rb ^ 1) * 4096;
        char* h1w = hS1 + (rb ^ 1) * 4096;

        xv = xn;
        int tn = (t + 1 < SEQL) ? t + 1 : SEQL - 1;
        xn.p4 = *(const int4*)(xfp + (size_t)tn * 512);

        Pack8 ah0[4], ah1[4];
        #pragma unroll
        for (int kk = 0; kk < 4; ++kk) {
            ah0[kk].p4 = *(const int4*)(h0r + (rbase + ((kk*64 + 16*g4) ^ swz)));
            ah1[kk].p4 = *(const int4*)(h1r + (rbase + ((kk*64 + 16*g4) ^ swz)));
        }

        __builtin_amdgcn_s_setprio(1);
        // Phase A: L0 MFMAs
        f32x4 acc0[4];
        #pragma unroll
        for (int g = 0; g < 4; ++g) { float b = biasr0[g]; acc0[g] = (f32x4){b,b,b,b}; }
        #pragma unroll
        for (int g = 0; g < 4; ++g)
            acc0[g] = __builtin_amdgcn_mfma_f32_16x16x32_f16(xv.h, xWf[g].h, acc0[g], 0, 0, 0);
        #pragma unroll
        for (int kk = 0; kk < 4; ++kk)
            #pragma unroll
            for (int g = 0; g < 4; ++g)
                acc0[g] = __builtin_amdgcn_mfma_f32_16x16x32_f16(ah0[kk].h, recW0f[g][kk].h, acc0[g], 0, 0, 0);

        // Phase B: L1 input-term MFMAs (B-frags from LDS)
        f32x4 acc1[4];
        #pragma unroll
        for (int g = 0; g < 4; ++g) { float b = biasr1[g]; acc1[g] = (f32x4){b,b,b,b}; }
        #pragma unroll
        for (int kk = 0; kk < 4; ++kk)
            #pragma unroll
            for (int g = 0; g < 4; ++g) {
                Pack8 bB;
                bB.p4 = *(const int4*)(smem + inBbase + (g*4 + kk)*1024 + lane*16);
                acc1[g] = __builtin_amdgcn_mfma_f32_16x16x32_f16(ah0[kk].h, bB.h, acc1[g], 0, 0, 0);
            }

        // Phase C: L1 recurrent MFMAs interleaved with L0 activation rows
        #pragma unroll
        for (int kk = 0; kk < 4; ++kk) {
            #pragma unroll
            for (int g = 0; g < 4; ++g)
                acc1[g] = __builtin_amdgcn_mfma_f32_16x16x32_f16(ah1[kk].h, recW1f[g][kk].h, acc1[g], 0, 0, 0);
            float si = fsig(acc0[0][kk]), sf = fsig(acc0[1][kk]);
            float tg = ftanh(acc0[2][kk]), so = fsig(acc0[3][kk]);
            float cc = sf * cst0[kk] + si * tg;
            cst0[kk] = cc;
            float hh = so * ftanh(cc);
            *(_Float16*)(h0w + woff[kk]) = (_Float16)hh;
        }
        __builtin_amdgcn_s_setprio(0);

        // Phase D: L1 activations
        #pragma unroll
        for (int r = 0; r < 4; ++r) {
            float si = fsig(acc1[0][r]), sf = fsig(acc1[1][r]);
            float tg = ftanh(acc1[2][r]), so = fsig(acc1[3][r]);
            float cc = sf * cst1[r] + si * tg;
            cst1[r] = cc;
            float hh = so * ftanh(cc);
            *(_Float16*)(h1w + woff[r]) = (_Float16)hh;
        }
        __syncthreads();
    }

    // ---- epilogue t=512: L1 step 511 + FC head ----
    {
        const char* h0r = hS0;        // rb = 0
        const char* h1r = hS1;
        Pack8 ah0[4], ah1[4];
        #pragma unroll
        for (int kk = 0; kk < 4; ++kk) {
            ah0[kk].p4 = *(const int4*)(h0r + (rbase + ((kk*64 + 16*g4) ^ swz)));
            ah1[kk].p4 = *(const int4*)(h1r + (rbase + ((kk*64 + 16*g4) ^ swz)));
        }
        f32x4 acc1[4];
        #pragma unroll
        for (int g = 0; g < 4; ++g) { float b = biasr1[g]; acc1[g] = (f32x4){b,b,b,b}; }
        #pragma unroll
        for (int kk = 0; kk < 4; ++kk)
            #pragma unroll
            for (int g = 0; g < 4; ++g) {
                Pack8 bB;
                bB.p4 = *(const int4*)(smem + inBbase + (g*4 + kk)*1024 + lane*16);
                acc1[g] = __builtin_amdgcn_mfma_f32_16x16x32_f16(ah0[kk].h, bB.h, acc1[g], 0, 0, 0);
            }
        #pragma unroll
        for (int kk = 0; kk < 4; ++kk)
            #pragma unroll
            for (int g = 0; g < 4; ++g)
                acc1[g] = __builtin_amdgcn_mfma_f32_16x16x32_f16(ah1[kk].h, recW1f[g][kk].h, acc1[g], 0, 0, 0);
        __syncthreads();              // inL reads done; smem base reusable
        float* lastH = (float*)smem;  // [16][128]
        #pragma unroll
        for (int r = 0; r < 4; ++r) {
            float si = fsig(acc1[0][r]), sf = fsig(acc1[1][r]);
            float tg = ftanh(acc1[2][r]), so = fsig(acc1[3][r]);
            float cc = sf * cst1[r] + si * tg;
            float hh = so * ftanh(cc);
            lastH[(4*g4 + r) * HID + unit] = hh;
        }
        __syncthreads();
        float* fcb = (float*)(smem + 8192);   // [16][64]
        #pragma unroll
        for (int s = 0; s < 2; ++s) {
            int task = tid + s * TPB;
            int r = task >> 6, o = task & 63;
            float a = fc1_b[o];
            for (int k = 0; k < HID; ++k) a += lastH[r * HID + k] * fc1_w[o * HID + k];
            fcb[r * 64 + o] = fmaxf(a, 0.f);
        }
        __syncthreads();
        if (tid < MT) {
            float a = fc2_b[0];
            for (int k = 0; k < 64; ++k) a += fcb[tid * 64 + k] * fc2_w[k];
            out[row0 + tid] = a;
        }
    }
}

extern "C" void kernel_launch(void* const* d_in, const int* in_sizes, int n_in,
                              void* d_out, int out_size, void* d_ws, size_t ws_size,
                              hipStream_t stream) {
    const float* x     = (const float*)d_in[0];
    const float* w_ih0 = (const float*)d_in[1];
    const float* w_hh0 = (const float*)d_in[2];
    const float* b_ih0 = (const float*)d_in[3];
    const float* b_hh0 = (const float*)d_in[4];
    const float* w_ih1 = (const float*)d_in[5];
    const float* w_hh1 = (const float*)d_in[6];
    const float* b_ih1 = (const float*)d_in[7];
    const float* b_hh1 = (const float*)d_in[8];
    const float* fc1_w = (const float*)d_in[9];
    const float* fc1_b = (const float*)d_in[10];
    const float* fc2_w = (const float*)d_in[11];
    const float* fc2_b = (const float*)d_in[12];

    char* ws = (char*)d_ws;
    short* recW0 = (short*)(ws);                 // 128 KB
    short* recW1 = (short*)(ws + (128u << 10));  // 128 KB
    short* inW1  = (short*)(ws + (256u << 10));  // 128 KB
    short* xW0   = (short*)(ws + (384u << 10));  //  32 KB
    float* bias0 = (float*)(ws + (416u << 10));  //   2 KB
    float* bias1 = (float*)(ws + (418u << 10));  //   2 KB
    short* xf    = (short*)(ws + (1u << 20));    //  32 MB f16 x-frags

    static bool attr_set = false;
    if (!attr_set) {
        hipFuncSetAttribute((const void*)fused_lstm_kernel,
                            hipFuncAttributeMaxDynamicSharedMemorySize, 147456);
        attr_set = true;
    }

    prep_kernel<<<8300, 256, 0, stream>>>(x, w_ih0, w_hh0, b_ih0, b_hh0,
                                          w_ih1, w_hh1, b_ih1, b_hh1,
                                          recW0, recW1, inW1, xW0, bias0, bias1, xf);
    fused_lstm_kernel<<<64, TPB, 147456, stream>>>(xf, recW0, recW1, inW1, xW0,
                                                   bias0, bias1,
                                                   fc1_w, fc1_b, fc2_w, fc2_b,
                                                   (float*)d_out);
}

// Round 6
// 1317.382 us; speedup vs baseline: 1.0345x; 1.0345x over previous
//
#include <hip/hip_runtime.h>

#define HID   128
#define SEQL  512
#define MT    16
#define TPB   1024
#define BATCH 1024

typedef __attribute__((ext_vector_type(4))) float    f32x4;
typedef __attribute__((ext_vector_type(8))) _Float16 f16x8;

union Pack8 { int2 p2[2]; int4 p4; f16x8 h; _Float16 hf[8]; short s[8]; };

__device__ __forceinline__ short f2hs(float f) {
    _Float16 v = (_Float16)f;
    return __builtin_bit_cast(short, v);
}
// R3/R5-proven activations (inf-safe; compiler-generated TRANS ops only)
__device__ __forceinline__ float fsig(float x) {
    return __builtin_amdgcn_rcpf(1.f + __expf(-x));
}
__device__ __forceinline__ float ftanh(float x) {
    return 1.f - 2.f * __builtin_amdgcn_rcpf(1.f + __expf(2.f * x));
}

// Repack weights into per-lane MFMA B-frag layout (fp16), sum biases,
// pre-pack x into fp16 A-frags. (Unchanged from R5 — proven.)
// 16x16x32 operand layout: lane l holds col=l&15, elem i -> k = kk*32 + 8*(l>>4) + i.
__global__ void prep_kernel(const float* __restrict__ x,
                            const float* __restrict__ w_ih0, const float* __restrict__ w_hh0,
                            const float* __restrict__ b_ih0, const float* __restrict__ b_hh0,
                            const float* __restrict__ w_ih1, const float* __restrict__ w_hh1,
                            const float* __restrict__ b_ih1, const float* __restrict__ b_hh1,
                            short* __restrict__ recW0, short* __restrict__ recW1,
                            short* __restrict__ inW1, short* __restrict__ xW0,
                            float* __restrict__ bias0, float* __restrict__ bias1,
                            short* __restrict__ xf) {
    int tid = blockIdx.x * 256 + threadIdx.x;
    if (tid < 2097152) {                    // x -> f16 frags [grp][t][c][g4][8]
        int g4 = tid & 3, c = (tid >> 2) & 15, t = (tid >> 6) & 511, grp = tid >> 15;
        const float* src = x + ((size_t)(grp * 16 + c) * 512 + t) * 32 + g4 * 8;
        Pack8 p;
        #pragma unroll
        for (int i = 0; i < 8; ++i) p.hf[i] = (_Float16)src[i];
        *(int4*)(xf + (size_t)tid * 8) = p.p4;
    } else if (tid < 2121728) {             // 3 matrices of [8w][4g][4kk][64lane][8]
        int q = tid - 2097152;
        int m = q >> 13;
        int r = q & 8191;
        int lane = r & 63, kk = (r >> 6) & 3, g = (r >> 8) & 3, w = r >> 10;
        int c = lane & 15, g4 = lane >> 4;
        int col = g * 128 + w * 16 + c;
        const float* src = (m == 0) ? w_hh0 : (m == 1) ? w_hh1 : w_ih1;
        short* dst = ((m == 0) ? recW0 : (m == 1) ? recW1 : inW1) + (size_t)r * 8;
        #pragma unroll
        for (int i = 0; i < 8; ++i)
            dst[i] = f2hs(src[col * 128 + kk * 32 + 8 * g4 + i]);
    } else if (tid < 2123776) {             // xW0: [8w][4g][64lane][8], K=32
        int r = tid - 2121728;
        int lane = r & 63, g = (r >> 6) & 3, w = r >> 8;
        int c = lane & 15, g4 = lane >> 4;
        int col = g * 128 + w * 16 + c;
        short* dst = xW0 + (size_t)r * 8;
        #pragma unroll
        for (int i = 0; i < 8; ++i)
            dst[i] = f2hs(w_ih0[col * 32 + 8 * g4 + i]);
    } else if (tid < 2124288) {
        int j = tid - 2123776;
        bias0[j] = b_ih0[j] + b_hh0[j];
    } else if (tid < 2124800) {
        int j = tid - 2124288;
        bias1[j] = b_ih1[j] + b_hh1[j];
    }
}

// Fused 2-layer LSTM, wave-specialized: one block = 16 batch rows, 16 waves.
// Waves 0-7 own L0 units [16w,16w+16); waves 8-15 own L1 units [16w',16w'+16).
// Iter t: L0 waves compute h0(t), L1 waves compute h1(t-1) from h0(t-1)/h1(t-2)
// in LDS (1-step skew). Each wave's weights fit registers (L0: 80, L1: 64);
// inW1 B-frags stay in LDS. Lane-local c/h update (D-layout col=lane&15,
// row=4*(lane>>4)+reg). One barrier per iter. 4 waves/SIMD for latency hiding.
__global__ __launch_bounds__(TPB) void fused_lstm_kernel(
    const short* __restrict__ xf,
    const short* __restrict__ recW0g, const short* __restrict__ recW1g,
    const short* __restrict__ inW1g,  const short* __restrict__ xW0g,
    const float* __restrict__ bias0,  const float* __restrict__ bias1,
    const float* __restrict__ fc1_w, const float* __restrict__ fc1_b,
    const float* __restrict__ fc2_w, const float* __restrict__ fc2_b,
    float* __restrict__ out)
{
    extern __shared__ char smem[];
    short* inL = (short*)smem;                   // 128 KB: inW1 B-frags
    char*  hS0 = smem + 131072;                  // 2 x 4 KB fp16 h0 state
    char*  hS1 = smem + 139264;                  // 2 x 4 KB fp16 h1 state

    const int tid = threadIdx.x;
    const int wv = tid >> 6, lane = tid & 63;
    const int c = lane & 15, g4 = lane >> 4;
    const int w = wv & 7;                        // unit-group within role
    const bool isL0 = (wv < 8);
    const int row0 = blockIdx.x * MT;

    // stage inW1 into LDS (16384 int4 over 1024 threads)
    #pragma unroll
    for (int i = 0; i < 16; ++i)
        ((int4*)inL)[i * TPB + tid] = ((const int4*)inW1g)[i * TPB + tid];
    // zero h0/h1 double buffers (16 KB = 4096 ints)
    #pragma unroll
    for (int i = 0; i < 4; ++i)
        ((int*)hS0)[i * TPB + tid] = 0;

    // role-specific loop-invariant register weights
    Pack8 recf[4][4];      // L0: recW0 frags; L1: recW1 frags
    Pack8 xWf[4];          // L0 only
    float biasr[4];
    if (isL0) {
        #pragma unroll
        for (int g = 0; g < 4; ++g)
            #pragma unroll
            for (int kk = 0; kk < 4; ++kk)
                recf[g][kk].p4 = *(const int4*)(recW0g + (size_t)((((w*4+g)*4+kk)*64 + lane) * 8));
        #pragma unroll
        for (int g = 0; g < 4; ++g)
            xWf[g].p4 = *(const int4*)(xW0g + (size_t)(((w*4+g)*64 + lane) * 8));
        #pragma unroll
        for (int g = 0; g < 4; ++g) biasr[g] = bias0[g*128 + w*16 + c];
    } else {
        #pragma unroll
        for (int g = 0; g < 4; ++g)
            #pragma unroll
            for (int kk = 0; kk < 4; ++kk)
                recf[g][kk].p4 = *(const int4*)(recW1g + (size_t)((((w*4+g)*4+kk)*64 + lane) * 8));
        #pragma unroll
        for (int g = 0; g < 4; ++g) biasr[g] = bias1[g*128 + w*16 + c];
    }

    __syncthreads();

    float cst[4] = {0.f, 0.f, 0.f, 0.f};

    const short* xfp = xf + (size_t)blockIdx.x * 262144 + c * 32 + g4 * 8;

    const int swz   = (c & 14) << 3;
    const int rbase = c * 256;
    const int unit  = w * 16 + c;
    int woff[4];
    #pragma unroll
    for (int r = 0; r < 4; ++r) {
        int rrow = 4 * g4 + r;
        woff[r] = rrow * 256 + ((unit * 2) ^ ((rrow & 14) << 3));
    }
    const int inBbase = w * 16384;

    Pack8 xv;
    if (isL0) xv.p4 = *(const int4*)(xfp);

    // ---- peel t=0: L0 waves only (h0(-1)=0 in zeroed buf0) ----
    if (isL0) {
        f32x4 acc[4];
        #pragma unroll
        for (int g = 0; g < 4; ++g) { float b = biasr[g]; acc[g] = (f32x4){b,b,b,b}; }
        #pragma unroll
        for (int g = 0; g < 4; ++g)
            acc[g] = __builtin_amdgcn_mfma_f32_16x16x32_f16(xv.h, xWf[g].h, acc[g], 0, 0, 0);
        xv.p4 = *(const int4*)(xfp + 512);           // x(1)
        #pragma unroll
        for (int kk = 0; kk < 4; ++kk) {
            Pack8 a;
            a.p4 = *(const int4*)(hS0 + (rbase + ((kk*64 + 16*g4) ^ swz)));
            #pragma unroll
            for (int g = 0; g < 4; ++g)
                acc[g] = __builtin_amdgcn_mfma_f32_16x16x32_f16(a.h, recf[g][kk].h, acc[g], 0, 0, 0);
        }
        char* h0w = hS0 + 4096;
        #pragma unroll
        for (int r = 0; r < 4; ++r) {
            float si = fsig(acc[0][r]), sf = fsig(acc[1][r]);
            float tg = ftanh(acc[2][r]), so = fsig(acc[3][r]);
            float cc = sf * cst[r] + si * tg;
            cst[r] = cc;
            float hh = so * ftanh(cc);
            *(_Float16*)(h0w + woff[r]) = (_Float16)hh;
        }
    }
    __syncthreads();

    // ---- steady iters t=1..511: L0 waves step t, L1 waves step t-1 ----
    for (int t = 1; t < SEQL; ++t) {
        const int rb = t & 1;
        if (isL0) {
            const char* h0r = hS0 + rb * 4096;
            char* h0w = hS0 + (rb ^ 1) * 4096;
            f32x4 acc[4];
            #pragma unroll
            for (int g = 0; g < 4; ++g) { float b = biasr[g]; acc[g] = (f32x4){b,b,b,b}; }
            #pragma unroll
            for (int g = 0; g < 4; ++g)
                acc[g] = __builtin_amdgcn_mfma_f32_16x16x32_f16(xv.h, xWf[g].h, acc[g], 0, 0, 0);
            int tn = (t + 1 < SEQL) ? t + 1 : SEQL - 1;
            xv.p4 = *(const int4*)(xfp + (size_t)tn * 512);   // prefetch x(t+1)
            #pragma unroll
            for (int kk = 0; kk < 4; ++kk) {
                Pack8 a;
                a.p4 = *(const int4*)(h0r + (rbase + ((kk*64 + 16*g4) ^ swz)));
                #pragma unroll
                for (int g = 0; g < 4; ++g)
                    acc[g] = __builtin_amdgcn_mfma_f32_16x16x32_f16(a.h, recf[g][kk].h, acc[g], 0, 0, 0);
            }
            #pragma unroll
            for (int r = 0; r < 4; ++r) {
                float si = fsig(acc[0][r]), sf = fsig(acc[1][r]);
                float tg = ftanh(acc[2][r]), so = fsig(acc[3][r]);
                float cc = sf * cst[r] + si * tg;
                cst[r] = cc;
                float hh = so * ftanh(cc);
                *(_Float16*)(h0w + woff[r]) = (_Float16)hh;
            }
        } else {
            const char* h0r = hS0 + rb * 4096;
            const char* h1r = hS1 + rb * 4096;
            char* h1w = hS1 + (rb ^ 1) * 4096;
            f32x4 acc[4];
            #pragma unroll
            for (int g = 0; g < 4; ++g) { float b = biasr[g]; acc[g] = (f32x4){b,b,b,b}; }
            // input term: A = h0(t-1), B-frags streamed from LDS
            #pragma unroll
            for (int kk = 0; kk < 4; ++kk) {
                Pack8 a0;
                a0.p4 = *(const int4*)(h0r + (rbase + ((kk*64 + 16*g4) ^ swz)));
                #pragma unroll
                for (int g = 0; g < 4; ++g) {
                    Pack8 bB;
                    bB.p4 = *(const int4*)(smem + inBbase + (g*4 + kk)*1024 + lane*16);
                    acc[g] = __builtin_amdgcn_mfma_f32_16x16x32_f16(a0.h, bB.h, acc[g], 0, 0, 0);
                }
            }
            // recurrent term: A = h1(t-2)
            #pragma unroll
            for (int kk = 0; kk < 4; ++kk) {
                Pack8 a1;
                a1.p4 = *(const int4*)(h1r + (rbase + ((kk*64 + 16*g4) ^ swz)));
                #pragma unroll
                for (int g = 0; g < 4; ++g)
                    acc[g] = __builtin_amdgcn_mfma_f32_16x16x32_f16(a1.h, recf[g][kk].h, acc[g], 0, 0, 0);
            }
            #pragma unroll
            for (int r = 0; r < 4; ++r) {
                float si = fsig(acc[0][r]), sf = fsig(acc[1][r]);
                float tg = ftanh(acc[2][r]), so = fsig(acc[3][r]);
                float cc = sf * cst[r] + si * tg;
                cst[r] = cc;
                float hh = so * ftanh(cc);
                *(_Float16*)(h1w + woff[r]) = (_Float16)hh;
            }
        }
        __syncthreads();
    }

    // ---- epilogue t=512: L1 waves compute h1(511); then FC head ----
    f32x4 accE[4];
    if (!isL0) {
        const char* h0r = hS0;        // rb = 0: h0(511), h1(510)
        const char* h1r = hS1;
        #pragma unroll
        for (int g = 0; g < 4; ++g) { float b = biasr[g]; accE[g] = (f32x4){b,b,b,b}; }
        #pragma unroll
        for (int kk = 0; kk < 4; ++kk) {
            Pack8 a0;
            a0.p4 = *(const int4*)(h0r + (rbase + ((kk*64 + 16*g4) ^ swz)));
            #pragma unroll
            for (int g = 0; g < 4; ++g) {
                Pack8 bB;
                bB.p4 = *(const int4*)(smem + inBbase + (g*4 + kk)*1024 + lane*16);
                accE[g] = __builtin_amdgcn_mfma_f32_16x16x32_f16(a0.h, bB.h, accE[g], 0, 0, 0);
            }
        }
        #pragma unroll
        for (int kk = 0; kk < 4; ++kk) {
            Pack8 a1;
            a1.p4 = *(const int4*)(h1r + (rbase + ((kk*64 + 16*g4) ^ swz)));
            #pragma unroll
            for (int g = 0; g < 4; ++g)
                accE[g] = __builtin_amdgcn_mfma_f32_16x16x32_f16(a1.h, recf[g][kk].h, accE[g], 0, 0, 0);
        }
    }
    __syncthreads();                  // all inL reads done; smem base reusable
    float* lastH = (float*)smem;      // [16][128]
    if (!isL0) {
        #pragma unroll
        for (int r = 0; r < 4; ++r) {
            float si = fsig(accE[0][r]), sf = fsig(accE[1][r]);
            float tg = ftanh(accE[2][r]), so = fsig(accE[3][r]);
            float cc = sf * cst[r] + si * tg;
            float hh = so * ftanh(cc);
            lastH[(4*g4 + r) * HID + unit] = hh;
        }
    }
    __syncthreads();
    float* fcb = (float*)(smem + 8192);   // [16][64]
    {
        int r = tid >> 6, o = tid & 63;
        float a = fc1_b[o];
        for (int k = 0; k < HID; ++k) a += lastH[r * HID + k] * fc1_w[o * HID + k];
        fcb[r * 64 + o] = fmaxf(a, 0.f);
    }
    __syncthreads();
    if (tid < MT) {
        float a = fc2_b[0];
        for (int k = 0; k < 64; ++k) a += fcb[tid * 64 + k] * fc2_w[k];
        out[row0 + tid] = a;
    }
}

extern "C" void kernel_launch(void* const* d_in, const int* in_sizes, int n_in,
                              void* d_out, int out_size, void* d_ws, size_t ws_size,
                              hipStream_t stream) {
    const float* x     = (const float*)d_in[0];
    const float* w_ih0 = (const float*)d_in[1];
    const float* w_hh0 = (const float*)d_in[2];
    const float* b_ih0 = (const float*)d_in[3];
    const float* b_hh0 = (const float*)d_in[4];
    const float* w_ih1 = (const float*)d_in[5];
    const float* w_hh1 = (const float*)d_in[6];
    const float* b_ih1 = (const float*)d_in[7];
    const float* b_hh1 = (const float*)d_in[8];
    const float* fc1_w = (const float*)d_in[9];
    const float* fc1_b = (const float*)d_in[10];
    const float* fc2_w = (const float*)d_in[11];
    const float* fc2_b = (const float*)d_in[12];

    char* ws = (char*)d_ws;
    short* recW0 = (short*)(ws);                 // 128 KB
    short* recW1 = (short*)(ws + (128u << 10));  // 128 KB
    short* inW1  = (short*)(ws + (256u << 10));  // 128 KB
    short* xW0   = (short*)(ws + (384u << 10));  //  32 KB
    float* bias0 = (float*)(ws + (416u << 10));  //   2 KB
    float* bias1 = (float*)(ws + (418u << 10));  //   2 KB
    short* xf    = (short*)(ws + (1u << 20));    //  32 MB f16 x-frags

    static bool attr_set = false;
    if (!attr_set) {
        hipFuncSetAttribute((const void*)fused_lstm_kernel,
                            hipFuncAttributeMaxDynamicSharedMemorySize, 147456);
        attr_set = true;
    }

    prep_kernel<<<8300, 256, 0, stream>>>(x, w_ih0, w_hh0, b_ih0, b_hh0,
                                          w_ih1, w_hh1, b_ih1, b_hh1,
                                          recW0, recW1, inW1, xW0, bias0, bias1, xf);
    fused_lstm_kernel<<<64, TPB, 147456, stream>>>(xf, recW0, recW1, inW1, xW0,
                                                   bias0, bias1,
                                                   fc1_w, fc1_b, fc2_w, fc2_b,
                                                   (float*)d_out);
}